// Round 3
// baseline (500.235 us; speedup 1.0000x reference)
//
#include <hip/hip_runtime.h>
#include <stdint.h>
#include <math.h>

// Problem constants (fixed by the reference: B=256, N=16384).
constexpr int BATCH = 256;
constexpr int NATOM = 16384;
constexpr int TPB   = 256;
constexpr int NQ    = 16;          // reduced quantities per batch
constexpr int C     = 4;           // blocks per batch
constexpr int ABLK  = NATOM / C;   // 4096 atoms per block
constexpr int GRAN  = 4;           // 4-atom granules per thread (16 atoms/thread)

// Deadlock-safety invariant: grid = BATCH*C = 1024 blocks; __launch_bounds__(256,4)
// guarantees 4 blocks/CU x 256 CU = 1024 co-resident blocks => the WHOLE grid is
// resident, so the per-batch spin below cannot deadlock under any dispatch order.

typedef float f32x4 __attribute__((ext_vector_type(4)));
typedef int   i32x4 __attribute__((ext_vector_type(4)));

// ---------------------------------------------------------------------------
// Accumulate 4 atoms into the 16 sums. Pred masking is redundant here: every
// term carries w, and w is zeroed for masked atoms (reference semantics).
// ---------------------------------------------------------------------------
__device__ __forceinline__ void accum4(
    const f32x4 p0, const f32x4 p1, const f32x4 p2,
    const f32x4 t0, const f32x4 t1, const f32x4 t2,
    const f32x4 wv, const i32x4 mv, float* acc)
{
    const float pf[12] = {p0.x,p0.y,p0.z,p0.w, p1.x,p1.y,p1.z,p1.w, p2.x,p2.y,p2.z,p2.w};
    const float tf[12] = {t0.x,t0.y,t0.z,t0.w, t1.x,t1.y,t1.z,t1.w, t2.x,t2.y,t2.z,t2.w};
    const float wf[4]  = {wv.x, wv.y, wv.z, wv.w};
    const int   mf[4]  = {mv.x, mv.y, mv.z, mv.w};
    #pragma unroll
    for (int k = 0; k < 4; ++k) {
        const float w  = (mf[k] != 0) ? wf[k] : 0.f;
        const float px = pf[3*k], py = pf[3*k+1], pz = pf[3*k+2];
        const float tx = tf[3*k], ty = tf[3*k+1], tz = tf[3*k+2];
        const float wtx = w * tx, wty = w * ty, wtz = w * tz;
        acc[0]  += w;
        acc[1]  += w * px;  acc[2]  += w * py;  acc[3]  += w * pz;
        acc[4]  += wtx;     acc[5]  += wty;     acc[6]  += wtz;
        acc[7]  += wtx*px;  acc[8]  += wtx*py;  acc[9]  += wtx*pz;
        acc[10] += wty*px;  acc[11] += wty*py;  acc[12] += wty*pz;
        acc[13] += wtz*px;  acc[14] += wtz*py;  acc[15] += wtz*pz;
    }
}

__device__ inline void jrot(double M[3][3], double V[3][3], int p, int q) {
    double mpq = M[p][q];
    if (fabs(mpq) < 1e-300) return;
    double theta = (M[q][q] - M[p][p]) / (2.0 * mpq);
    double t = copysign(1.0, theta) / (fabs(theta) + sqrt(theta * theta + 1.0));
    double c = 1.0 / sqrt(t * t + 1.0);
    double s = t * c;
    int r = 3 - p - q;
    double mpp = M[p][p], mqq = M[q][q], mrp = M[r][p], mrq = M[r][q];
    M[p][p] = mpp - t * mpq;
    M[q][q] = mqq + t * mpq;
    M[p][q] = M[q][p] = 0.0;
    double nrp = c * mrp - s * mrq;
    double nrq = s * mrp + c * mrq;
    M[r][p] = M[p][r] = nrp;
    M[r][q] = M[q][r] = nrq;
    #pragma unroll
    for (int i = 0; i < 3; ++i) {
        double vip = V[i][p], viq = V[i][q];
        V[i][p] = c * vip - s * viq;
        V[i][q] = s * vip + c * viq;
    }
}

#define LOADG(Sfx, g) do {                                                   \
    const long base_ = base0 + (long)(g) * (TPB * 4);                        \
    const f32x4* p4_ = reinterpret_cast<const f32x4*>(pred + base_ * 3);     \
    const f32x4* t4_ = reinterpret_cast<const f32x4*>(tru  + base_ * 3);     \
    p##Sfx##0 = p4_[0]; p##Sfx##1 = p4_[1]; p##Sfx##2 = p4_[2];              \
    t##Sfx##0 = t4_[0]; t##Sfx##1 = t4_[1]; t##Sfx##2 = t4_[2];              \
    w##Sfx = *reinterpret_cast<const f32x4*>(wgt + base_);                   \
    m##Sfx = *reinterpret_cast<const i32x4*>(mask + base_);                  \
} while (0)

// ---------------------------------------------------------------------------
// Fused kernel:
//   phase 1: 16-quantity partial sums (2-stage pipelined loads)
//   phase 2: last-arriving block per batch solves Kabsch in fp64, release-flag
//   phase 3: blocks spin (bounded) on their batch flag, re-read pred/mask
//            (L3-resident), rotate, nontemporal store
// ---------------------------------------------------------------------------
__global__ __launch_bounds__(TPB, 4) void wra_fused(
    const float* __restrict__ pred, const float* __restrict__ tru,
    const float* __restrict__ wgt, const int* __restrict__ mask,
    int* cnt, int* flag, float* partials, float* consts,
    float* __restrict__ out)
{
    const int blk = blockIdx.x;
    const int b   = blk >> 2;          // / C
    const int s   = blk & 3;           // % C
    const int tid = threadIdx.x;
    const long base0 = (long)b * NATOM + (long)s * ABLK + (long)tid * 4;

    // ---- phase 1 ----
    float acc[NQ];
    #pragma unroll
    for (int k = 0; k < NQ; ++k) acc[k] = 0.f;

    f32x4 pA0, pA1, pA2, tA0, tA1, tA2, wA;
    f32x4 pB0, pB1, pB2, tB0, tB1, tB2, wB;
    i32x4 mA, mB;

    LOADG(A, 0);
    LOADG(B, 1);
    accum4(pA0, pA1, pA2, tA0, tA1, tA2, wA, mA, acc);
    LOADG(A, 2);
    accum4(pB0, pB1, pB2, tB0, tB1, tB2, wB, mB, acc);
    LOADG(B, 3);
    accum4(pA0, pA1, pA2, tA0, tA1, tA2, wA, mA, acc);
    accum4(pB0, pB1, pB2, tB0, tB1, tB2, wB, mB, acc);

    // wave reduce to 4 lanes (4 shuffle steps), finish via LDS
    #pragma unroll
    for (int off = 32; off >= 4; off >>= 1) {
        #pragma unroll
        for (int k = 0; k < NQ; ++k)
            acc[k] += __shfl_down(acc[k], off, 64);
    }
    __shared__ float red[16][NQ + 1];
    const int wave = tid >> 6, lane = tid & 63;
    if (lane < 4) {
        #pragma unroll
        for (int k = 0; k < NQ; ++k) red[wave * 4 + lane][k] = acc[k];
    }
    __syncthreads();
    if (tid < NQ) {
        float ssum = 0.f;
        #pragma unroll
        for (int r = 0; r < 16; ++r) ssum += red[r][tid];
        partials[blk * NQ + tid] = ssum;
    }
    __threadfence();                   // publish partials device-wide

    // ---- phase 2: last-arriving block of this batch solves ----
    __shared__ int amLast;
    __syncthreads();
    if (tid == 0) {
        int prev = __hip_atomic_fetch_add(&cnt[b], 1, __ATOMIC_ACQ_REL,
                                          __HIP_MEMORY_SCOPE_AGENT);
        amLast = (prev == C - 1);
    }
    __syncthreads();

    if (amLast) {
        __shared__ double q[NQ];
        if (tid < NQ) {
            double sum = 0.0;
            for (int cidx = 0; cidx < C; ++cidx)
                sum += (double)partials[(b * C + cidx) * NQ + tid];
            q[tid] = sum;
        }
        __syncthreads();
        if (tid == 0) {
            double wsum = q[0];
            double pc[3], tc[3];
            for (int j = 0; j < 3; ++j) { pc[j] = q[1+j] / wsum; tc[j] = q[4+j] / wsum; }

            double Cv[3][3];
            for (int i = 0; i < 3; ++i)
                for (int j = 0; j < 3; ++j)
                    Cv[i][j] = q[7 + 3*i + j] - wsum * tc[i] * pc[j];

            double M[3][3];
            for (int i = 0; i < 3; ++i)
                for (int j = 0; j < 3; ++j)
                    M[i][j] = Cv[0][i]*Cv[0][j] + Cv[1][i]*Cv[1][j] + Cv[2][i]*Cv[2][j];
            double V[3][3] = {{1,0,0},{0,1,0},{0,0,1}};
            for (int sweep = 0; sweep < 12; ++sweep) {
                double off = M[0][1]*M[0][1] + M[0][2]*M[0][2] + M[1][2]*M[1][2];
                double diag = M[0][0] + M[1][1] + M[2][2];
                if (off <= 1e-28 * diag * diag) break;
                jrot(M, V, 0, 1);
                jrot(M, V, 0, 2);
                jrot(M, V, 1, 2);
            }
            double lam[3] = {M[0][0], M[1][1], M[2][2]};
            int i0 = 0, i1 = 1, i2 = 2, tmp;
            if (lam[i0] < lam[i1]) { tmp = i0; i0 = i1; i1 = tmp; }
            if (lam[i0] < lam[i2]) { tmp = i0; i0 = i2; i2 = tmp; }
            if (lam[i1] < lam[i2]) { tmp = i1; i1 = i2; i2 = tmp; }
            double v0[3] = {V[0][i0], V[1][i0], V[2][i0]};
            double v1[3] = {V[0][i1], V[1][i1], V[2][i1]};
            double v2[3] = {V[0][i2], V[1][i2], V[2][i2]};

            double u0[3], u1[3];
            for (int i = 0; i < 3; ++i) {
                u0[i] = Cv[i][0]*v0[0] + Cv[i][1]*v0[1] + Cv[i][2]*v0[2];
                u1[i] = Cv[i][0]*v1[0] + Cv[i][1]*v1[1] + Cv[i][2]*v1[2];
            }
            double n0 = sqrt(u0[0]*u0[0] + u0[1]*u0[1] + u0[2]*u0[2]);
            for (int i = 0; i < 3; ++i) u0[i] /= n0;
            double d01 = u1[0]*u0[0] + u1[1]*u0[1] + u1[2]*u0[2];
            for (int i = 0; i < 3; ++i) u1[i] -= d01 * u0[i];
            double n1 = sqrt(u1[0]*u1[0] + u1[1]*u1[1] + u1[2]*u1[2]);
            for (int i = 0; i < 3; ++i) u1[i] /= n1;

            // Reflection fix: U' third col = sign(det V) * (u0 x u1); equals
            // U diag(1,1,d) V^T with d = sign(det U det V) exactly.
            double detV = v0[0]*(v1[1]*v2[2] - v1[2]*v2[1])
                        - v0[1]*(v1[0]*v2[2] - v1[2]*v2[0])
                        + v0[2]*(v1[0]*v2[1] - v1[1]*v2[0]);
            double sV = (detV >= 0.0) ? 1.0 : -1.0;
            double u2[3] = { sV * (u0[1]*u1[2] - u0[2]*u1[1]),
                             sV * (u0[2]*u1[0] - u0[0]*u1[2]),
                             sV * (u0[0]*u1[1] - u0[1]*u1[0]) };

            float* o = consts + b * 15;
            for (int i = 0; i < 3; ++i)
                for (int j = 0; j < 3; ++j)
                    o[3*i + j] = (float)(u0[i]*v0[j] + u1[i]*v1[j] + u2[i]*v2[j]);
            for (int j = 0; j < 3; ++j) { o[9 + j] = (float)pc[j]; o[12 + j] = (float)tc[j]; }

            __threadfence();           // publish consts before the flag
            __hip_atomic_store(&flag[b], 1, __ATOMIC_RELEASE,
                               __HIP_MEMORY_SCOPE_AGENT);
        }
    }

    // ---- phase 3: bounded spin on this batch's flag, then apply ----
    if (tid == 0) {
        int iter = 0;
        while (__hip_atomic_load(&flag[b], __ATOMIC_ACQUIRE,
                                 __HIP_MEMORY_SCOPE_AGENT) == 0) {
            __builtin_amdgcn_s_sleep(16);
            if (++iter > (1 << 20)) break;   // ~0.4s bound: fail visibly, never hang
        }
    }
    __syncthreads();

    __shared__ float cst[15];
    if (tid < 15) cst[tid] = consts[b * 15 + tid];
    __syncthreads();

    const float pcx = cst[9],  pcy = cst[10], pcz = cst[11];
    const float tcx = cst[12], tcy = cst[13], tcz = cst[14];

    #pragma unroll
    for (int g = 0; g < GRAN; ++g) {
        const long base = base0 + (long)g * (TPB * 4);
        const f32x4* p4 = reinterpret_cast<const f32x4*>(pred + base * 3);
        f32x4 P0 = p4[0], P1 = p4[1], P2 = p4[2];
        i32x4 mv = *reinterpret_cast<const i32x4*>(mask + base);

        const float pf[12] = {P0.x,P0.y,P0.z,P0.w, P1.x,P1.y,P1.z,P1.w,
                              P2.x,P2.y,P2.z,P2.w};
        const int   mf[4]  = {mv.x, mv.y, mv.z, mv.w};
        float O[12];
        #pragma unroll
        for (int k = 0; k < 4; ++k) {
            const float px = (mf[k] ? pf[3*k]   : 0.f) - pcx;
            const float py = (mf[k] ? pf[3*k+1] : 0.f) - pcy;
            const float pz = (mf[k] ? pf[3*k+2] : 0.f) - pcz;
            O[3*k]     = px * cst[0] + py * cst[3] + pz * cst[6] + tcx;
            O[3*k + 1] = px * cst[1] + py * cst[4] + pz * cst[7] + tcy;
            O[3*k + 2] = px * cst[2] + py * cst[5] + pz * cst[8] + tcz;
        }
        f32x4* o4 = reinterpret_cast<f32x4*>(out + base * 3);
        f32x4 o0 = {O[0], O[1], O[2],  O[3]};
        f32x4 o1 = {O[4], O[5], O[6],  O[7]};
        f32x4 o2 = {O[8], O[9], O[10], O[11]};
        __builtin_nontemporal_store(o0, o4 + 0);
        __builtin_nontemporal_store(o1, o4 + 1);
        __builtin_nontemporal_store(o2, o4 + 2);
    }
}

extern "C" void kernel_launch(void* const* d_in, const int* in_sizes, int n_in,
                              void* d_out, int out_size, void* d_ws, size_t ws_size,
                              hipStream_t stream) {
    const float* pred = (const float*)d_in[0];
    const float* tru  = (const float*)d_in[1];
    const float* wgt  = (const float*)d_in[2];
    const int*   mask = (const int*)d_in[3];   // bool input -> int32 per harness
    float* out = (float*)d_out;

    // workspace: [cnt 256 i32][flag 256 i32][partials 1024*16 f32][consts 256*15 f32]
    int*   cnt      = (int*)d_ws;
    int*   flag     = cnt + BATCH;
    float* partials = (float*)(flag + BATCH);
    float* consts   = partials + BATCH * C * NQ;

    hipMemsetAsync(d_ws, 0, 2 * BATCH * sizeof(int), stream);
    hipLaunchKernelGGL(wra_fused, dim3(BATCH * C), dim3(TPB), 0, stream,
                       pred, tru, wgt, mask, cnt, flag, partials, consts, out);
}

// Round 4
// 204.259 us; speedup vs baseline: 2.4490x; 2.4490x over previous
//
#include <hip/hip_runtime.h>
#include <stdint.h>
#include <math.h>

// Problem constants (fixed by the reference: B=256, N=16384).
constexpr int BATCH = 256;
constexpr int NATOM = 16384;
constexpr int TPB   = 256;
constexpr int NQ    = 16;          // reduced quantities per batch
constexpr int C1    = 4;           // pass-A blocks (chunks) per batch
constexpr int ABLK  = NATOM / C1;  // 4096 atoms per pass-A block
constexpr int GRAN  = 4;           // 4-atom granules per thread (16 atoms/thread)

typedef float f32x4 __attribute__((ext_vector_type(4)));
typedef int   i32x4 __attribute__((ext_vector_type(4)));

// ---------------------------------------------------------------------------
// Pass A: per-chunk partial sums of 16 quantities:
//   q[0]=sum w; q[1..3]=sum w*p; q[4..6]=sum w*t; q[7+3i+j]=sum w*t_i*p_j
// Masked atoms contribute 0 (every term carries w, and w:=0 when masked).
// mask arrives as int32 (harness converts bool -> int).
// ---------------------------------------------------------------------------
__global__ __launch_bounds__(TPB) void wra_partials(
    const float* __restrict__ pred, const float* __restrict__ tru,
    const float* __restrict__ wgt, const int* __restrict__ mask,
    float* __restrict__ partials)
{
    const int blk = blockIdx.x;
    const int b   = blk >> 2;          // / C1
    const int s   = blk & 3;           // % C1
    const int tid = threadIdx.x;

    float acc[NQ];
    #pragma unroll
    for (int k = 0; k < NQ; ++k) acc[k] = 0.f;

    #pragma unroll 2
    for (int it = 0; it < GRAN; ++it) {
        const long base = (long)b * NATOM + (long)s * ABLK
                        + (long)it * (TPB * 4) + (long)tid * 4;

        const f32x4* p4 = reinterpret_cast<const f32x4*>(pred + base * 3);
        const f32x4* t4 = reinterpret_cast<const f32x4*>(tru  + base * 3);
        f32x4 pA = p4[0], pB = p4[1], pC = p4[2];
        f32x4 tA = t4[0], tB = t4[1], tC = t4[2];
        f32x4 wv = *reinterpret_cast<const f32x4*>(wgt + base);
        i32x4 mv = *reinterpret_cast<const i32x4*>(mask + base);

        const float pf[12] = {pA.x,pA.y,pA.z,pA.w, pB.x,pB.y,pB.z,pB.w,
                              pC.x,pC.y,pC.z,pC.w};
        const float tf[12] = {tA.x,tA.y,tA.z,tA.w, tB.x,tB.y,tB.z,tB.w,
                              tC.x,tC.y,tC.z,tC.w};
        const float wf[4]  = {wv.x, wv.y, wv.z, wv.w};
        const int   mf[4]  = {mv.x, mv.y, mv.z, mv.w};

        #pragma unroll
        for (int k = 0; k < 4; ++k) {
            const float w  = (mf[k] != 0) ? wf[k] : 0.f;
            const float px = pf[3*k], py = pf[3*k+1], pz = pf[3*k+2];
            const float tx = tf[3*k], ty = tf[3*k+1], tz = tf[3*k+2];
            const float wtx = w * tx, wty = w * ty, wtz = w * tz;
            acc[0]  += w;
            acc[1]  += w * px;  acc[2]  += w * py;  acc[3]  += w * pz;
            acc[4]  += wtx;     acc[5]  += wty;     acc[6]  += wtz;
            acc[7]  += wtx*px;  acc[8]  += wtx*py;  acc[9]  += wtx*pz;
            acc[10] += wty*px;  acc[11] += wty*py;  acc[12] += wty*pz;
            acc[13] += wtz*px;  acc[14] += wtz*py;  acc[15] += wtz*pz;
        }
    }

    // wave reduce to 4 lanes (4 shuffle steps), finish via LDS
    #pragma unroll
    for (int off = 32; off >= 4; off >>= 1) {
        #pragma unroll
        for (int k = 0; k < NQ; ++k)
            acc[k] += __shfl_down(acc[k], off, 64);
    }
    __shared__ float red[16][NQ + 1];
    const int wave = tid >> 6, lane = tid & 63;
    if (lane < 4) {
        #pragma unroll
        for (int k = 0; k < NQ; ++k) red[wave * 4 + lane][k] = acc[k];
    }
    __syncthreads();
    if (tid < NQ) {
        float ssum = 0.f;
        #pragma unroll
        for (int r = 0; r < 16; ++r) ssum += red[r][tid];
        partials[blk * NQ + tid] = ssum;
    }
}

// ---------------------------------------------------------------------------
// fp64 Jacobi rotation helper for the 3x3 symmetric eigenproblem
// ---------------------------------------------------------------------------
__device__ inline void jrot(double M[3][3], double V[3][3], int p, int q) {
    double mpq = M[p][q];
    if (fabs(mpq) < 1e-300) return;
    double theta = (M[q][q] - M[p][p]) / (2.0 * mpq);
    double t = copysign(1.0, theta) / (fabs(theta) + sqrt(theta * theta + 1.0));
    double c = 1.0 / sqrt(t * t + 1.0);
    double s = t * c;
    int r = 3 - p - q;
    double mpp = M[p][p], mqq = M[q][q], mrp = M[r][p], mrq = M[r][q];
    M[p][p] = mpp - t * mpq;
    M[q][q] = mqq + t * mpq;
    M[p][q] = M[q][p] = 0.0;
    double nrp = c * mrp - s * mrq;
    double nrq = s * mrp + c * mrq;
    M[r][p] = M[p][r] = nrp;
    M[r][q] = M[q][r] = nrq;
    #pragma unroll
    for (int i = 0; i < 3; ++i) {
        double vip = V[i][p], viq = V[i][q];
        V[i][p] = c * vip - s * viq;
        V[i][q] = s * vip + c * viq;
    }
}

// ---------------------------------------------------------------------------
// Pass B: fused solve + apply. Each block REDUNDANTLY solves its batch's 3x3
// Kabsch problem from the 64 partial floats (thread 0, fp64, runs in parallel
// across all blocks -> wall cost of one solve), then applies
//   out = p_masked @ R + d,   d = tc - pc @ R
// to its chunk. No cross-block sync, no consts roundtrip, no memset.
// pred/mask are L3-resident from pass A; output stored nontemporal.
// ---------------------------------------------------------------------------
__global__ __launch_bounds__(TPB) void wra_solve_apply(
    const float* __restrict__ pred, const int* __restrict__ mask,
    const float* __restrict__ partials, float* __restrict__ out)
{
    const int blk = blockIdx.x;
    const int b   = blk >> 2;          // / C1 (4 apply blocks per batch)
    const int s   = blk & 3;
    const int tid = threadIdx.x;

    __shared__ double q[NQ];
    __shared__ float cst[12];          // R row-major (9) + d (3)

    if (tid < NQ) {
        double sum = 0.0;
        #pragma unroll
        for (int c = 0; c < C1; ++c)
            sum += (double)partials[(b * C1 + c) * NQ + tid];
        q[tid] = sum;
    }
    __syncthreads();

    if (tid == 0) {
        const double wsum = q[0];
        double pc[3], tc[3];
        for (int j = 0; j < 3; ++j) { pc[j] = q[1+j] / wsum; tc[j] = q[4+j] / wsum; }

        double Cv[3][3];
        for (int i = 0; i < 3; ++i)
            for (int j = 0; j < 3; ++j)
                Cv[i][j] = q[7 + 3*i + j] - wsum * tc[i] * pc[j];

        // M = C^T C (symmetric PSD); Jacobi eigendecomposition M = V diag V^T
        double M[3][3];
        for (int i = 0; i < 3; ++i)
            for (int j = 0; j < 3; ++j)
                M[i][j] = Cv[0][i]*Cv[0][j] + Cv[1][i]*Cv[1][j] + Cv[2][i]*Cv[2][j];
        double V[3][3] = {{1,0,0},{0,1,0},{0,0,1}};
        for (int sweep = 0; sweep < 12; ++sweep) {
            double off = M[0][1]*M[0][1] + M[0][2]*M[0][2] + M[1][2]*M[1][2];
            double diag = M[0][0] + M[1][1] + M[2][2];
            if (off <= 1e-28 * diag * diag) break;
            jrot(M, V, 0, 1);
            jrot(M, V, 0, 2);
            jrot(M, V, 1, 2);
        }
        double lam[3] = {M[0][0], M[1][1], M[2][2]};
        int i0 = 0, i1 = 1, i2 = 2, tmp;
        if (lam[i0] < lam[i1]) { tmp = i0; i0 = i1; i1 = tmp; }
        if (lam[i0] < lam[i2]) { tmp = i0; i0 = i2; i2 = tmp; }
        if (lam[i1] < lam[i2]) { tmp = i1; i1 = i2; i2 = tmp; }
        double v0[3] = {V[0][i0], V[1][i0], V[2][i0]};
        double v1[3] = {V[0][i1], V[1][i1], V[2][i1]};
        double v2[3] = {V[0][i2], V[1][i2], V[2][i2]};

        double u0[3], u1[3];
        for (int i = 0; i < 3; ++i) {
            u0[i] = Cv[i][0]*v0[0] + Cv[i][1]*v0[1] + Cv[i][2]*v0[2];
            u1[i] = Cv[i][0]*v1[0] + Cv[i][1]*v1[1] + Cv[i][2]*v1[2];
        }
        double n0 = sqrt(u0[0]*u0[0] + u0[1]*u0[1] + u0[2]*u0[2]);
        for (int i = 0; i < 3; ++i) u0[i] /= n0;
        double d01 = u1[0]*u0[0] + u1[1]*u0[1] + u1[2]*u0[2];
        for (int i = 0; i < 3; ++i) u1[i] -= d01 * u0[i];
        double n1 = sqrt(u1[0]*u1[0] + u1[1]*u1[1] + u1[2]*u1[2]);
        for (int i = 0; i < 3; ++i) u1[i] /= n1;

        // Reflection fix: U' third col = sign(det V) * (u0 x u1); equals
        // U diag(1,1,d) V^T with d = sign(det U det V) exactly.
        double detV = v0[0]*(v1[1]*v2[2] - v1[2]*v2[1])
                    - v0[1]*(v1[0]*v2[2] - v1[2]*v2[0])
                    + v0[2]*(v1[0]*v2[1] - v1[1]*v2[0]);
        double sV = (detV >= 0.0) ? 1.0 : -1.0;
        double u2[3] = { sV * (u0[1]*u1[2] - u0[2]*u1[1]),
                         sV * (u0[2]*u1[0] - u0[0]*u1[2]),
                         sV * (u0[0]*u1[1] - u0[1]*u1[0]) };

        double R[3][3];
        for (int i = 0; i < 3; ++i)
            for (int j = 0; j < 3; ++j)
                R[i][j] = u0[i]*v0[j] + u1[i]*v1[j] + u2[i]*v2[j];
        for (int i = 0; i < 3; ++i)
            for (int j = 0; j < 3; ++j)
                cst[3*i + j] = (float)R[i][j];
        for (int j = 0; j < 3; ++j)
            cst[9 + j] = (float)(tc[j] - (pc[0]*R[0][j] + pc[1]*R[1][j]
                                                        + pc[2]*R[2][j]));
    }
    __syncthreads();

    const float dx = cst[9], dy = cst[10], dz = cst[11];

    #pragma unroll 2
    for (int g = 0; g < GRAN; ++g) {
        const long base = (long)b * NATOM + (long)s * ABLK
                        + (long)g * (TPB * 4) + (long)tid * 4;
        const f32x4* p4 = reinterpret_cast<const f32x4*>(pred + base * 3);
        f32x4 P0 = p4[0], P1 = p4[1], P2 = p4[2];
        i32x4 mv = *reinterpret_cast<const i32x4*>(mask + base);

        const float pf[12] = {P0.x,P0.y,P0.z,P0.w, P1.x,P1.y,P1.z,P1.w,
                              P2.x,P2.y,P2.z,P2.w};
        const int   mf[4]  = {mv.x, mv.y, mv.z, mv.w};
        float O[12];
        #pragma unroll
        for (int k = 0; k < 4; ++k) {
            const float px = mf[k] ? pf[3*k]   : 0.f;
            const float py = mf[k] ? pf[3*k+1] : 0.f;
            const float pz = mf[k] ? pf[3*k+2] : 0.f;
            O[3*k]     = px * cst[0] + py * cst[3] + pz * cst[6] + dx;
            O[3*k + 1] = px * cst[1] + py * cst[4] + pz * cst[7] + dy;
            O[3*k + 2] = px * cst[2] + py * cst[5] + pz * cst[8] + dz;
        }
        f32x4* o4 = reinterpret_cast<f32x4*>(out + base * 3);
        f32x4 o0 = {O[0], O[1], O[2],  O[3]};
        f32x4 o1 = {O[4], O[5], O[6],  O[7]};
        f32x4 o2 = {O[8], O[9], O[10], O[11]};
        __builtin_nontemporal_store(o0, o4 + 0);
        __builtin_nontemporal_store(o1, o4 + 1);
        __builtin_nontemporal_store(o2, o4 + 2);
    }
}

extern "C" void kernel_launch(void* const* d_in, const int* in_sizes, int n_in,
                              void* d_out, int out_size, void* d_ws, size_t ws_size,
                              hipStream_t stream) {
    const float* pred = (const float*)d_in[0];
    const float* tru  = (const float*)d_in[1];
    const float* wgt  = (const float*)d_in[2];
    const int*   mask = (const int*)d_in[3];   // bool input -> int32 per harness
    float* out = (float*)d_out;

    float* partials = (float*)d_ws;            // BATCH*C1*NQ floats = 64 KB

    hipLaunchKernelGGL(wra_partials, dim3(BATCH * C1), dim3(TPB), 0, stream,
                       pred, tru, wgt, mask, partials);
    hipLaunchKernelGGL(wra_solve_apply, dim3(BATCH * C1), dim3(TPB), 0, stream,
                       pred, mask, partials, out);
}

// Round 5
// 190.460 us; speedup vs baseline: 2.6265x; 1.0725x over previous
//
#include <hip/hip_runtime.h>
#include <stdint.h>
#include <math.h>

// Problem constants (fixed by the reference: B=256, N=16384).
constexpr int BATCH = 256;
constexpr int NATOM = 16384;
constexpr int TPB   = 256;
constexpr int NQ    = 16;          // reduced quantities per batch

// Pass-A geometry: 8 chunks/batch -> 2048 blocks = 8 blocks/CU (full 32
// waves/CU residency in ONE generation), 8 atoms/thread in 2 granules.
constexpr int C1    = 8;
constexpr int ABLK1 = NATOM / C1;  // 2048 atoms per pass-A block

// Pass-C geometry: 16 chunks/batch -> 4096 blocks, 4 atoms/thread.
constexpr int C3    = 16;
constexpr int ABLK3 = NATOM / C3;  // 1024

typedef float f32x4 __attribute__((ext_vector_type(4)));
typedef int   i32x4 __attribute__((ext_vector_type(4)));

// ---------------------------------------------------------------------------
// Pass A: per-chunk partial sums of 16 quantities:
//   q[0]=sum w; q[1..3]=sum w*p; q[4..6]=sum w*t; q[7+3i+j]=sum w*t_i*p_j
// Masked atoms contribute 0 (every term carries w, w:=0 when masked).
// mask arrives as int32 (harness converts bool -> int).
// Both granules' loads are issued before any use: 16 x 16B in flight/lane.
// ---------------------------------------------------------------------------
__global__ __launch_bounds__(TPB) void wra_partials(
    const float* __restrict__ pred, const float* __restrict__ tru,
    const float* __restrict__ wgt, const int* __restrict__ mask,
    float* __restrict__ partials)
{
    const int blk = blockIdx.x;
    const int b   = blk >> 3;          // / C1
    const int s   = blk & 7;           // % C1
    const int tid = threadIdx.x;
    const long baseA = (long)b * NATOM + (long)s * ABLK1 + (long)tid * 4;
    const long baseB = baseA + TPB * 4;

    const f32x4* pa4 = reinterpret_cast<const f32x4*>(pred + baseA * 3);
    const f32x4* ta4 = reinterpret_cast<const f32x4*>(tru  + baseA * 3);
    const f32x4* pb4 = reinterpret_cast<const f32x4*>(pred + baseB * 3);
    const f32x4* tb4 = reinterpret_cast<const f32x4*>(tru  + baseB * 3);

    // granule A loads
    f32x4 pA0 = pa4[0], pA1 = pa4[1], pA2 = pa4[2];
    f32x4 tA0 = ta4[0], tA1 = ta4[1], tA2 = ta4[2];
    f32x4 wA  = *reinterpret_cast<const f32x4*>(wgt + baseA);
    i32x4 mA  = *reinterpret_cast<const i32x4*>(mask + baseA);
    // granule B loads (issued before any use of A)
    f32x4 pB0 = pb4[0], pB1 = pb4[1], pB2 = pb4[2];
    f32x4 tB0 = tb4[0], tB1 = tb4[1], tB2 = tb4[2];
    f32x4 wB  = *reinterpret_cast<const f32x4*>(wgt + baseB);
    i32x4 mB  = *reinterpret_cast<const i32x4*>(mask + baseB);

    float acc[NQ];
    #pragma unroll
    for (int k = 0; k < NQ; ++k) acc[k] = 0.f;

    {
        const float pf[12] = {pA0.x,pA0.y,pA0.z,pA0.w, pA1.x,pA1.y,pA1.z,pA1.w,
                              pA2.x,pA2.y,pA2.z,pA2.w};
        const float tf[12] = {tA0.x,tA0.y,tA0.z,tA0.w, tA1.x,tA1.y,tA1.z,tA1.w,
                              tA2.x,tA2.y,tA2.z,tA2.w};
        const float wf[4]  = {wA.x, wA.y, wA.z, wA.w};
        const int   mf[4]  = {mA.x, mA.y, mA.z, mA.w};
        #pragma unroll
        for (int k = 0; k < 4; ++k) {
            const float w  = (mf[k] != 0) ? wf[k] : 0.f;
            const float px = pf[3*k], py = pf[3*k+1], pz = pf[3*k+2];
            const float tx = tf[3*k], ty = tf[3*k+1], tz = tf[3*k+2];
            const float wtx = w * tx, wty = w * ty, wtz = w * tz;
            acc[0]  += w;
            acc[1]  += w * px;  acc[2]  += w * py;  acc[3]  += w * pz;
            acc[4]  += wtx;     acc[5]  += wty;     acc[6]  += wtz;
            acc[7]  += wtx*px;  acc[8]  += wtx*py;  acc[9]  += wtx*pz;
            acc[10] += wty*px;  acc[11] += wty*py;  acc[12] += wty*pz;
            acc[13] += wtz*px;  acc[14] += wtz*py;  acc[15] += wtz*pz;
        }
    }
    {
        const float pf[12] = {pB0.x,pB0.y,pB0.z,pB0.w, pB1.x,pB1.y,pB1.z,pB1.w,
                              pB2.x,pB2.y,pB2.z,pB2.w};
        const float tf[12] = {tB0.x,tB0.y,tB0.z,tB0.w, tB1.x,tB1.y,tB1.z,tB1.w,
                              tB2.x,tB2.y,tB2.z,tB2.w};
        const float wf[4]  = {wB.x, wB.y, wB.z, wB.w};
        const int   mf[4]  = {mB.x, mB.y, mB.z, mB.w};
        #pragma unroll
        for (int k = 0; k < 4; ++k) {
            const float w  = (mf[k] != 0) ? wf[k] : 0.f;
            const float px = pf[3*k], py = pf[3*k+1], pz = pf[3*k+2];
            const float tx = tf[3*k], ty = tf[3*k+1], tz = tf[3*k+2];
            const float wtx = w * tx, wty = w * ty, wtz = w * tz;
            acc[0]  += w;
            acc[1]  += w * px;  acc[2]  += w * py;  acc[3]  += w * pz;
            acc[4]  += wtx;     acc[5]  += wty;     acc[6]  += wtz;
            acc[7]  += wtx*px;  acc[8]  += wtx*py;  acc[9]  += wtx*pz;
            acc[10] += wty*px;  acc[11] += wty*py;  acc[12] += wty*pz;
            acc[13] += wtz*px;  acc[14] += wtz*py;  acc[15] += wtz*pz;
        }
    }

    // wave reduce to 4 lanes (4 shuffle steps = 64 DS ops/thread), LDS tail
    #pragma unroll
    for (int off = 32; off >= 4; off >>= 1) {
        #pragma unroll
        for (int k = 0; k < NQ; ++k)
            acc[k] += __shfl_down(acc[k], off, 64);
    }
    __shared__ float red[16][NQ + 1];
    const int wave = tid >> 6, lane = tid & 63;
    if (lane < 4) {
        #pragma unroll
        for (int k = 0; k < NQ; ++k) red[wave * 4 + lane][k] = acc[k];
    }
    __syncthreads();
    if (tid < NQ) {
        float ssum = 0.f;
        #pragma unroll
        for (int r = 0; r < 16; ++r) ssum += red[r][tid];
        partials[blk * NQ + tid] = ssum;
    }
}

// ---------------------------------------------------------------------------
// fp64 Jacobi rotation helper for the 3x3 symmetric eigenproblem
// ---------------------------------------------------------------------------
__device__ inline void jrot(double M[3][3], double V[3][3], int p, int q) {
    double mpq = M[p][q];
    if (fabs(mpq) < 1e-300) return;
    double theta = (M[q][q] - M[p][p]) / (2.0 * mpq);
    double t = copysign(1.0, theta) / (fabs(theta) + sqrt(theta * theta + 1.0));
    double c = 1.0 / sqrt(t * t + 1.0);
    double s = t * c;
    int r = 3 - p - q;
    double mpp = M[p][p], mqq = M[q][q], mrp = M[r][p], mrq = M[r][q];
    M[p][p] = mpp - t * mpq;
    M[q][q] = mqq + t * mpq;
    M[p][q] = M[q][p] = 0.0;
    double nrp = c * mrp - s * mrq;
    double nrq = s * mrp + c * mrq;
    M[r][p] = M[p][r] = nrp;
    M[r][q] = M[q][r] = nrq;
    #pragma unroll
    for (int i = 0; i < 3; ++i) {
        double vip = V[i][p], viq = V[i][q];
        V[i][p] = c * vip - s * viq;
        V[i][q] = s * vip + c * viq;
    }
}

// ---------------------------------------------------------------------------
// Pass B: one lane per batch (4 blocks x 64 threads). Reduce the C1 chunk
// partials in fp64, solve the 3x3 Kabsch problem, write 12 consts:
// R row-major (9) + d (3) where d = tc - pc @ R.
// ---------------------------------------------------------------------------
__global__ __launch_bounds__(64) void wra_solve(
    const float* __restrict__ partials, float* __restrict__ consts)
{
    const int b = blockIdx.x * 64 + threadIdx.x;
    if (b >= BATCH) return;

    double q[NQ];
    #pragma unroll
    for (int k = 0; k < NQ; ++k) {
        double sum = 0.0;
        #pragma unroll
        for (int c = 0; c < C1; ++c)
            sum += (double)partials[(b * C1 + c) * NQ + k];
        q[k] = sum;
    }

    const double wsum = q[0];
    double pc[3], tc[3];
    for (int j = 0; j < 3; ++j) { pc[j] = q[1+j] / wsum; tc[j] = q[4+j] / wsum; }

    double Cv[3][3];
    for (int i = 0; i < 3; ++i)
        for (int j = 0; j < 3; ++j)
            Cv[i][j] = q[7 + 3*i + j] - wsum * tc[i] * pc[j];

    double M[3][3];
    for (int i = 0; i < 3; ++i)
        for (int j = 0; j < 3; ++j)
            M[i][j] = Cv[0][i]*Cv[0][j] + Cv[1][i]*Cv[1][j] + Cv[2][i]*Cv[2][j];
    double V[3][3] = {{1,0,0},{0,1,0},{0,0,1}};
    for (int sweep = 0; sweep < 12; ++sweep) {
        double off = M[0][1]*M[0][1] + M[0][2]*M[0][2] + M[1][2]*M[1][2];
        double diag = M[0][0] + M[1][1] + M[2][2];
        if (off <= 1e-28 * diag * diag) break;
        jrot(M, V, 0, 1);
        jrot(M, V, 0, 2);
        jrot(M, V, 1, 2);
    }
    double lam[3] = {M[0][0], M[1][1], M[2][2]};
    int i0 = 0, i1 = 1, i2 = 2, tmp;
    if (lam[i0] < lam[i1]) { tmp = i0; i0 = i1; i1 = tmp; }
    if (lam[i0] < lam[i2]) { tmp = i0; i0 = i2; i2 = tmp; }
    if (lam[i1] < lam[i2]) { tmp = i1; i1 = i2; i2 = tmp; }
    double v0[3] = {V[0][i0], V[1][i0], V[2][i0]};
    double v1[3] = {V[0][i1], V[1][i1], V[2][i1]};
    double v2[3] = {V[0][i2], V[1][i2], V[2][i2]};

    double u0[3], u1[3];
    for (int i = 0; i < 3; ++i) {
        u0[i] = Cv[i][0]*v0[0] + Cv[i][1]*v0[1] + Cv[i][2]*v0[2];
        u1[i] = Cv[i][0]*v1[0] + Cv[i][1]*v1[1] + Cv[i][2]*v1[2];
    }
    double n0 = sqrt(u0[0]*u0[0] + u0[1]*u0[1] + u0[2]*u0[2]);
    for (int i = 0; i < 3; ++i) u0[i] /= n0;
    double d01 = u1[0]*u0[0] + u1[1]*u0[1] + u1[2]*u0[2];
    for (int i = 0; i < 3; ++i) u1[i] -= d01 * u0[i];
    double n1 = sqrt(u1[0]*u1[0] + u1[1]*u1[1] + u1[2]*u1[2]);
    for (int i = 0; i < 3; ++i) u1[i] /= n1;

    // Reflection fix: U' third col = sign(det V) * (u0 x u1); equals
    // U diag(1,1,d) V^T with d = sign(det U det V) exactly.
    double detV = v0[0]*(v1[1]*v2[2] - v1[2]*v2[1])
                - v0[1]*(v1[0]*v2[2] - v1[2]*v2[0])
                + v0[2]*(v1[0]*v2[1] - v1[1]*v2[0]);
    double sV = (detV >= 0.0) ? 1.0 : -1.0;
    double u2[3] = { sV * (u0[1]*u1[2] - u0[2]*u1[1]),
                     sV * (u0[2]*u1[0] - u0[0]*u1[2]),
                     sV * (u0[0]*u1[1] - u0[1]*u1[0]) };

    double R[3][3];
    for (int i = 0; i < 3; ++i)
        for (int j = 0; j < 3; ++j)
            R[i][j] = u0[i]*v0[j] + u1[i]*v1[j] + u2[i]*v2[j];

    float* o = consts + b * 12;
    for (int i = 0; i < 3; ++i)
        for (int j = 0; j < 3; ++j)
            o[3*i + j] = (float)R[i][j];
    for (int j = 0; j < 3; ++j)
        o[9 + j] = (float)(tc[j] - (pc[0]*R[0][j] + pc[1]*R[1][j]
                                                  + pc[2]*R[2][j]));
}

// ---------------------------------------------------------------------------
// Pass C: out = p_masked @ R + d. Pure streaming; pred/mask are L2/L3-warm
// from pass A; output never re-read -> nontemporal stores.
// ---------------------------------------------------------------------------
__global__ __launch_bounds__(TPB) void wra_apply(
    const float* __restrict__ pred, const int* __restrict__ mask,
    const float* __restrict__ consts, float* __restrict__ out)
{
    const int blk = blockIdx.x;
    const int b   = blk >> 4;          // / C3
    const int s   = blk & 15;          // % C3
    const int tid = threadIdx.x;

    __shared__ float cst[12];
    if (tid < 12) cst[tid] = consts[b * 12 + tid];
    __syncthreads();

    const long base = (long)b * NATOM + (long)s * ABLK3 + (long)tid * 4;
    const f32x4* p4 = reinterpret_cast<const f32x4*>(pred + base * 3);
    f32x4 P0 = p4[0], P1 = p4[1], P2 = p4[2];
    i32x4 mv = *reinterpret_cast<const i32x4*>(mask + base);

    const float pf[12] = {P0.x,P0.y,P0.z,P0.w, P1.x,P1.y,P1.z,P1.w,
                          P2.x,P2.y,P2.z,P2.w};
    const int   mf[4]  = {mv.x, mv.y, mv.z, mv.w};
    const float dx = cst[9], dy = cst[10], dz = cst[11];

    float O[12];
    #pragma unroll
    for (int k = 0; k < 4; ++k) {
        const float px = mf[k] ? pf[3*k]   : 0.f;
        const float py = mf[k] ? pf[3*k+1] : 0.f;
        const float pz = mf[k] ? pf[3*k+2] : 0.f;
        O[3*k]     = px * cst[0] + py * cst[3] + pz * cst[6] + dx;
        O[3*k + 1] = px * cst[1] + py * cst[4] + pz * cst[7] + dy;
        O[3*k + 2] = px * cst[2] + py * cst[5] + pz * cst[8] + dz;
    }
    f32x4* o4 = reinterpret_cast<f32x4*>(out + base * 3);
    f32x4 o0 = {O[0], O[1], O[2],  O[3]};
    f32x4 o1 = {O[4], O[5], O[6],  O[7]};
    f32x4 o2 = {O[8], O[9], O[10], O[11]};
    __builtin_nontemporal_store(o0, o4 + 0);
    __builtin_nontemporal_store(o1, o4 + 1);
    __builtin_nontemporal_store(o2, o4 + 2);
}

extern "C" void kernel_launch(void* const* d_in, const int* in_sizes, int n_in,
                              void* d_out, int out_size, void* d_ws, size_t ws_size,
                              hipStream_t stream) {
    const float* pred = (const float*)d_in[0];
    const float* tru  = (const float*)d_in[1];
    const float* wgt  = (const float*)d_in[2];
    const int*   mask = (const int*)d_in[3];   // bool input -> int32 per harness
    float* out = (float*)d_out;

    float* partials = (float*)d_ws;            // BATCH*C1*NQ floats = 128 KB
    float* consts   = partials + BATCH * C1 * NQ;  // BATCH*12 floats

    hipLaunchKernelGGL(wra_partials, dim3(BATCH * C1), dim3(TPB), 0, stream,
                       pred, tru, wgt, mask, partials);
    hipLaunchKernelGGL(wra_solve, dim3(BATCH / 64), dim3(64), 0, stream,
                       partials, consts);
    hipLaunchKernelGGL(wra_apply, dim3(BATCH * C3), dim3(TPB), 0, stream,
                       pred, mask, consts, out);
}